// Round 10
// baseline (85.675 us; speedup 1.0000x reference)
//
#include <hip/hip_runtime.h>

#define NROWS 8192
#define DDIM  64
#define KNN   32
#define MAXIT 100

// alpha/beta arrive as 1-element arrays; robust to int32 or float32 encoding.
__device__ __forceinline__ float scalar_val(const void* p) {
    int iv = *(const int*)p;
    if (iv > -1000000 && iv < 1000000) return (float)iv;
    return *(const float*)p;
}

// One block = 8 rows of A. Wave-role split (no barriers, no atomics):
//   waves 2,3 : ZERO-STREAM role. Loads = idx only (consumed before any
//               store). Build per-lane hitmask, stream float4 zeros for all
//               NON-hit chunks of 4 rows each. Saturates HBM from t~1us.
//   waves 0,1 : COMPUTE role. 2 rows per half-wave: coop gathers, Newton,
//               dedupe, embs, Yout, then merged stores for HIT chunks only.
// Hit/non-hit partition is a pure function of idx -> computed identically by
// both roles -> every chunk of A written exactly once. Load-consumes never
// follow bulk stores in any wave (in-order vmcnt is never crossed).
__global__ __launch_bounds__(256, 4) void school_fused_kernel(
    const float* __restrict__ Y,
    const float* __restrict__ semH,
    const float* __restrict__ orthoH,
    const int*   __restrict__ idx,
    const void*  alpha_p,
    const void*  beta_p,
    float* __restrict__ embs,   // N*D
    float* __restrict__ A,      // N*N
    float* __restrict__ Yout)   // N*D
{
    __shared__ int    col_s[8][KNN];
    __shared__ float  ad_s[8][KNN];
    __shared__ float2 cw_s[8][KNN];     // packed {bitcast(col), w_deduped}
    __shared__ int    zcol[2][2][64];   // [stream wave][pass][slot]

    const int tid  = threadIdx.x;
    const int wv   = tid >> 6;          // wave id 0..3
    const int row0 = blockIdx.x * 8;

    if (wv >= 2) {
        // ================= ZERO-STREAM ROLE (waves 2,3) =================
        const int wz = wv - 2;          // 0,1
        const int L  = tid & 63;
        const int h  = L >> 5;          // half-wave
        const int j  = L & 31;
        const int ra0 = wz * 4 + h;     // pass-0 row (block-relative)
        const int ra1 = wz * 4 + 2 + h; // pass-1 row

        // ---- all loads up front (only these; consumed before stores) ----
        const int c0 = idx[(row0 + ra0) * 64 + 1 + j];
        const int c1 = idx[(row0 + ra1) * 64 + 1 + j];
        zcol[wz][0][L] = c0;
        zcol[wz][1][L] = c1;

        // ---- hitmasks for my two rows (LDS broadcast reads: lgkmcnt) ----
        unsigned long long m0 = 0ull, m1 = 0ull;
        #pragma unroll 1
        for (int jj = 0; jj < 32; ++jj) {
            int a = zcol[wz][0][h * 32 + jj];
            int b = zcol[wz][1][h * 32 + jj];
            if (((a >> 2) & 31) == j) m0 |= 1ull << (a >> 7);
            if (((b >> 2) & 31) == j) m1 |= 1ull << (b >> 7);
        }

        // ---- pure zero streams (non-hit chunks; ~63/64 of all chunks) ----
        const float4 z4 = make_float4(0.f, 0.f, 0.f, 0.f);
        float4* R0 = (float4*)(A + (size_t)(row0 + ra0) * NROWS);
        float4* R1 = (float4*)(A + (size_t)(row0 + ra1) * NROWS);
        #pragma unroll 8
        for (int ss = 0; ss < 64; ++ss)
            if (!((m0 >> ss) & 1ull)) R0[(ss << 5) + j] = z4;
        #pragma unroll 8
        for (int ss = 0; ss < 64; ++ss)
            if (!((m1 >> ss) & 1ull)) R1[(ss << 5) + j] = z4;
        return;
    }

    // ================= COMPUTE ROLE (waves 0,1) =================
    const int hw = tid >> 5;            // half-wave 0..3
    const int j  = tid & 31;

    const float alpha = scalar_val(alpha_p);
    const float beta  = scalar_val(beta_p);

    const float4* Y4 = (const float4*)Y;
    const float4* O4 = (const float4*)orthoH;

    // ---- A1: per-row front (distances -> Newton -> dedupe -> cw_s) ----
    #pragma unroll 1
    for (int rr = 0; rr < 2; ++rr) {
        const int row_rel = hw * 2 + rr;
        const int row     = row0 + row_rel;

        const int col = idx[row * 64 + 1 + j];   // idxa0 = idx[:, 1:33]
        col_s[row_rel][j] = col;

        const int q = j & 15, g = j >> 4;
        const float4 ownY = Y4[(size_t)row * 16 + q];
        const float4 ownO = O4[(size_t)row * 16 + q];

        #pragma unroll 4
        for (int t = 0; t < 16; ++t) {
            const int c = col_s[row_rel][2 * t + g];
            const float4 gY = Y4[(size_t)c * 16 + q];
            const float4 gO = O4[(size_t)c * 16 + q];
            float ex = ownY.x - gY.x, ey = ownY.y - gY.y,
                  ez = ownY.z - gY.z, ew = ownY.w - gY.w;
            float dY = ex * ex + ey * ey + ez * ez + ew * ew;
            ex = ownO.x - gO.x; ey = ownO.y - gO.y;
            ez = ownO.z - gO.z; ew = ownO.w - gO.w;
            float dO = ex * ex + ey * ey + ez * ez + ew * ew;
            #pragma unroll
            for (int mm = 1; mm <= 8; mm <<= 1) {
                dY += __shfl_xor(dY, mm, 64);
                dO += __shfl_xor(dO, mm, 64);
            }
            if ((j & 15) == 0) {
                float dfv = sqrtf(dY + 1e-8f);
                float dxv = sqrtf(dO + 1e-8f);
                ad_s[row_rel][2 * t + g] = -(dxv + beta * dfv) / (2.f * alpha);
            }
        }
        const float ad = ad_s[row_rel][j];

        // simplex projection (32 lanes = one row)
        float s = ad;
        #pragma unroll
        for (int mm = 1; mm <= 16; mm <<= 1) s += __shfl_xor(s, mm, 64);
        const float v0 = ad - s * (1.f / 32.f) + (1.f / 32.f);

        float lam = 0.f;
        #pragma unroll 1
        for (int it = 0; it < MAXIT; ++it) {
            float v1 = v0 - lam;
            float p = v1 > 0.f ? v1 : 0.f;
            float c = v1 > 0.f ? 1.f : 0.f;
            #pragma unroll
            for (int mm = 1; mm <= 16; mm <<= 1) {
                p += __shfl_xor(p, mm, 64);
                c += __shfl_xor(c, mm, 64);
            }
            float step = (p - 1.f) / fmaxf(c, 1.f);
            lam += step;
            if (__all(fabsf(step) <= 1e-6f ? 1 : 0)) break;
        }
        const float w = fmaxf(v0 - lam, 0.f);

        // dedupe (np fancy-assignment: last j wins)
        bool dead = false;
        for (int jj = j + 1; jj < 32; ++jj)
            dead |= (col_s[row_rel][jj] == col);
        cw_s[row_rel][j] = make_float2(__int_as_float(col), dead ? 0.f : w);
    }

    // ---- A2: embs (gather loads consumed BEFORE any bulk store) ----
    {
        const float2* H2 = (const float2*)semH;
        #pragma unroll 1
        for (int rr = 0; rr < 2; ++rr) {
            const int row_rel = hw * 2 + rr;
            const int row     = row0 + row_rel;
            float2 acc = make_float2(0.f, 0.f);
            #pragma unroll 4
            for (int jj = 0; jj < KNN; ++jj) {
                float2 cw = cw_s[row_rel][jj];
                int   c   = __float_as_int(cw.x);
                float wv  = cw.y;
                float2 hl = H2[(size_t)c * 32 + j];
                acc.x += wv * hl.x;
                acc.y += wv * hl.y;
            }
            ((float2*)embs)[(size_t)row * 32 + j] = acc;
        }
    }

    // ---- A3: Y passthrough (8 rows = 256 float2, 128 threads x 2) ----
    {
        const float2* Y2 = (const float2*)(Y + (size_t)row0 * DDIM);
        float2* O2 = (float2*)(Yout + (size_t)row0 * DDIM);
        O2[tid]       = Y2[tid];
        O2[tid + 128] = Y2[tid + 128];
    }

    // ---- A4: HIT-chunk merged stores (data from LDS -> lgkmcnt only) ----
    #pragma unroll 1
    for (int rr = 0; rr < 2; ++rr) {
        const int row_rel = hw * 2 + rr;
        const int row     = row0 + row_rel;

        // k-slot scan (ascending jj => ascending apply = np last-wins)
        unsigned long long hm = 0ull;
        unsigned k0 = 0xFFFFFFFFu, k1 = 0xFFFFFFFFu,
                 k2 = 0xFFFFFFFFu, k3 = 0xFFFFFFFFu;
        float f0 = 0.f, f1 = 0.f, f2 = 0.f, f3 = 0.f;
        int nhit = 0;
        #pragma unroll 1
        for (int jj = 0; jj < 32; ++jj) {
            float2 cw = cw_s[row_rel][jj];
            int c = __float_as_int(cw.x);
            if (((c >> 2) & 31) == j) {
                hm |= 1ull << (c >> 7);
                unsigned key = ((unsigned)(c >> 7) << 2) | (unsigned)(c & 3);
                float wvv = cw.y;
                k3 = (nhit == 3) ? key : k3;  f3 = (nhit == 3) ? wvv : f3;
                k2 = (nhit == 2) ? key : k2;  f2 = (nhit == 2) ? wvv : f2;
                k1 = (nhit == 1) ? key : k1;  f1 = (nhit == 1) ? wvv : f1;
                k0 = (nhit == 0) ? key : k0;  f0 = (nhit == 0) ? wvv : f0;
                nhit++;
            }
        }

        // merged zero+value stores for hit chunks (E[popcount]=1 per lane)
        {
            float4* Arow4 = (float4*)(A + (size_t)row * NROWS);
            unsigned long long mrem = hm;
            while (mrem) {
                int ss = __ffsll(mrem) - 1;
                mrem &= mrem - 1;
                float4 v = make_float4(0.f, 0.f, 0.f, 0.f);
                #define APPLY_SLOT(kk, ff)                                   \
                    if ((int)(kk >> 2) == ss) {                              \
                        int p_ = (int)(kk & 3u);                             \
                        v.x = (p_ == 0) ? ff : v.x;                          \
                        v.y = (p_ == 1) ? ff : v.y;                          \
                        v.z = (p_ == 2) ? ff : v.z;                          \
                        v.w = (p_ == 3) ? ff : v.w;                          \
                    }
                APPLY_SLOT(k0, f0)
                APPLY_SLOT(k1, f1)
                APPLY_SLOT(k2, f2)
                APPLY_SLOT(k3, f3)
                #undef APPLY_SLOT
                Arow4[(ss << 5) + j] = v;
            }
        }

        // rare overflow (>4 cols on one lane): ordered dword fixups
        if (nhit > 4) {
            asm volatile("s_waitcnt vmcnt(0)" ::: "memory");
            int cnt = 0;
            for (int jj = 0; jj < 32; ++jj) {
                float2 cw = cw_s[row_rel][jj];
                int c = __float_as_int(cw.x);
                if (((c >> 2) & 31) == j) {
                    if (cnt >= 4) {
                        A[(size_t)row * NROWS + c] = cw.y;
                        asm volatile("s_waitcnt vmcnt(0)" ::: "memory");
                    }
                    cnt++;
                }
            }
        }
    }
}

extern "C" void kernel_launch(void* const* d_in, const int* in_sizes, int n_in,
                              void* d_out, int out_size, void* d_ws, size_t ws_size,
                              hipStream_t stream) {
    const float* Y      = (const float*)d_in[0];
    const float* semH   = (const float*)d_in[1];
    const float* orthoH = (const float*)d_in[2];
    const int*   idx    = (const int*)d_in[3];
    const void*  alpha  = d_in[4];
    const void*  beta   = d_in[5];

    float* out  = (float*)d_out;
    float* embs = out;                                   // N*D
    float* A    = out + (size_t)NROWS * DDIM;            // N*N
    float* Yout = A + (size_t)NROWS * NROWS;             // N*D

    school_fused_kernel<<<NROWS / 8, 256, 0, stream>>>(
        Y, semH, orthoH, idx, alpha, beta, embs, A, Yout);
}

// Round 11
// 68.630 us; speedup vs baseline: 1.2483x; 1.2483x over previous
//
#include <hip/hip_runtime.h>

#define NROWS 8192
#define DDIM  64
#define KNN   32
#define MAXIT 100

// alpha/beta arrive as 1-element arrays; robust to int32 or float32 encoding.
__device__ __forceinline__ float scalar_val(const void* p) {
    int iv = *(const int*)p;
    if (iv > -1000000 && iv < 1000000) return (float)iv;
    return *(const float*)p;
}

// ============ K1: compute front. distances -> Newton -> dedupe -> ws,
//               embs, Ypass. No A traffic. ============
__global__ __launch_bounds__(256, 4) void school_compute_kernel(
    const float* __restrict__ Y,
    const float* __restrict__ semH,
    const float* __restrict__ orthoH,
    const int*   __restrict__ idx,
    const void*  alpha_p,
    const void*  beta_p,
    float* __restrict__ embs,   // N*D
    float2* __restrict__ ws,    // N*KNN packed {bitcast(col), w}
    float* __restrict__ Yout)   // N*D
{
    __shared__ int    col_s[8][KNN];
    __shared__ float  ad_s[8][KNN];
    __shared__ float2 cw_s[8][KNN];

    const int tid  = threadIdx.x;
    const int j    = tid & 31;
    const int r    = tid >> 5;
    const int row0 = blockIdx.x * 8;
    const int row  = row0 + r;

    const float alpha = scalar_val(alpha_p);
    const float beta  = scalar_val(beta_p);

    // neighbor ids
    const int col = idx[row * 64 + 1 + j];       // idxa0 = idx[:, 1:33]
    col_s[r][j] = col;

    // distances, cooperative-coalesced (2 cols per 16-lane group)
    const float4* Y4 = (const float4*)Y;
    const float4* O4 = (const float4*)orthoH;
    const int q = j & 15, g = j >> 4;
    const float4 ownY = Y4[(size_t)row * 16 + q];
    const float4 ownO = O4[(size_t)row * 16 + q];

    #pragma unroll 4
    for (int t = 0; t < 16; ++t) {
        const int c = col_s[r][2 * t + g];
        const float4 gY = Y4[(size_t)c * 16 + q];
        const float4 gO = O4[(size_t)c * 16 + q];
        float ex = ownY.x - gY.x, ey = ownY.y - gY.y,
              ez = ownY.z - gY.z, ew = ownY.w - gY.w;
        float dY = ex * ex + ey * ey + ez * ez + ew * ew;
        ex = ownO.x - gO.x; ey = ownO.y - gO.y;
        ez = ownO.z - gO.z; ew = ownO.w - gO.w;
        float dO = ex * ex + ey * ey + ez * ez + ew * ew;
        #pragma unroll
        for (int mm = 1; mm <= 8; mm <<= 1) {
            dY += __shfl_xor(dY, mm, 64);
            dO += __shfl_xor(dO, mm, 64);
        }
        if ((j & 15) == 0) {
            float dfv = sqrtf(dY + 1e-8f);
            float dxv = sqrtf(dO + 1e-8f);
            ad_s[r][2 * t + g] = -(dxv + beta * dfv) / (2.f * alpha);
        }
    }
    const float ad = ad_s[r][j];

    // simplex projection
    float s = ad;
    #pragma unroll
    for (int mm = 1; mm <= 16; mm <<= 1) s += __shfl_xor(s, mm, 64);
    const float v0 = ad - s * (1.f / 32.f) + (1.f / 32.f);

    float lam = 0.f;
    #pragma unroll 1
    for (int it = 0; it < MAXIT; ++it) {
        float v1 = v0 - lam;
        float p = v1 > 0.f ? v1 : 0.f;
        float c = v1 > 0.f ? 1.f : 0.f;
        #pragma unroll
        for (int mm = 1; mm <= 16; mm <<= 1) {
            p += __shfl_xor(p, mm, 64);
            c += __shfl_xor(c, mm, 64);
        }
        float step = (p - 1.f) / fmaxf(c, 1.f);
        lam += step;
        if (__all(fabsf(step) <= 1e-6f ? 1 : 0)) break;
    }
    const float w = fmaxf(v0 - lam, 0.f);

    // dedupe (np fancy-assignment: last j wins)
    bool dead = false;
    for (int jj = j + 1; jj < 32; ++jj)
        dead |= (col_s[r][jj] == col);
    const float2 cw = make_float2(__int_as_float(col), dead ? 0.f : w);
    cw_s[r][j] = cw;
    ws[(size_t)row * KNN + j] = cw;      // compact handoff to K2

    // embs_hom[row] = sum_j w_j * semH[col_j]
    {
        float2 acc = make_float2(0.f, 0.f);
        const float2* H2 = (const float2*)semH;
        #pragma unroll 4
        for (int jj = 0; jj < KNN; ++jj) {
            float2 c2 = cw_s[r][jj];
            int   c   = __float_as_int(c2.x);
            float wv  = c2.y;
            float2 h = H2[(size_t)c * 32 + j];
            acc.x += wv * h.x;
            acc.y += wv * h.y;
        }
        ((float2*)embs)[(size_t)row * 32 + j] = acc;
    }

    // Y passthrough
    {
        const float2* Y2 = (const float2*)(Y + (size_t)row0 * DDIM);
        float2* O2 = (float2*)(Yout + (size_t)row0 * DDIM);
        O2[tid] = Y2[tid];
    }
}

// ============ K2: expand. Tiny prologue (ws read + k-slot scan), then the
//               unconditional merged zero+scatter stream at fill rate. ============
__global__ __launch_bounds__(256, 4) void school_expand_kernel(
    const float2* __restrict__ ws,
    float* __restrict__ A)
{
    __shared__ float2 cw_s[8][KNN];

    const int tid  = threadIdx.x;
    const int j    = tid & 31;
    const int r    = tid >> 5;
    const int row  = blockIdx.x * 8 + r;

    const float2 mycw = ws[(size_t)row * KNN + j];
    cw_s[r][j] = mycw;

    // k-slot scan (ascending jj => ascending apply = np last-wins)
    // Lane j owns float4 chunks i = 32*ss + j; col c -> owner (c>>2)&31,
    // ss = c>>7, pos = c&3.
    unsigned k0 = 0xFFFFFFFFu, k1 = 0xFFFFFFFFu, k2 = 0xFFFFFFFFu, k3 = 0xFFFFFFFFu;
    float f0 = 0.f, f1 = 0.f, f2 = 0.f, f3 = 0.f;
    int nhit = 0;
    #pragma unroll 1
    for (int jj = 0; jj < 32; ++jj) {
        float2 cw = cw_s[r][jj];
        int c = __float_as_int(cw.x);
        if (((c >> 2) & 31) == j) {
            unsigned key = ((unsigned)(c >> 7) << 2) | (unsigned)(c & 3);
            float wv = cw.y;
            k3 = (nhit == 3) ? key : k3;  f3 = (nhit == 3) ? wv : f3;
            k2 = (nhit == 2) ? key : k2;  f2 = (nhit == 2) ? wv : f2;
            k1 = (nhit == 1) ? key : k1;  f1 = (nhit == 1) ? wv : f1;
            k0 = (nhit == 0) ? key : k0;  f0 = (nhit == 0) ? wv : f0;
            nhit++;
        }
    }

    // merged zero+scatter stream (unconditional 64 float4/lane)
    {
        float4* Arow4 = (float4*)(A + (size_t)row * NROWS);
        #pragma unroll 4
        for (int ss = 0; ss < 64; ++ss) {
            float4 v = make_float4(0.f, 0.f, 0.f, 0.f);
            #define APPLY_SLOT(kk, ff)                                   \
                if ((kk >> 2) == (unsigned)ss) {                         \
                    int p_ = (int)(kk & 3u);                             \
                    v.x = (p_ == 0) ? ff : v.x;                          \
                    v.y = (p_ == 1) ? ff : v.y;                          \
                    v.z = (p_ == 2) ? ff : v.z;                          \
                    v.w = (p_ == 3) ? ff : v.w;                          \
                }
            APPLY_SLOT(k0, f0)
            APPLY_SLOT(k1, f1)
            APPLY_SLOT(k2, f2)
            APPLY_SLOT(k3, f3)
            #undef APPLY_SLOT
            Arow4[(ss << 5) + j] = v;
        }
    }

    // rare overflow (>4 cols on one lane): ordered dword fixups
    if (nhit > 4) {
        asm volatile("s_waitcnt vmcnt(0)" ::: "memory");
        int cnt = 0;
        for (int jj = 0; jj < 32; ++jj) {
            float2 cw = cw_s[r][jj];
            int c = __float_as_int(cw.x);
            if (((c >> 2) & 31) == j) {
                if (cnt >= 4) {
                    A[(size_t)row * NROWS + c] = cw.y;
                    asm volatile("s_waitcnt vmcnt(0)" ::: "memory");
                }
                cnt++;
            }
        }
    }
}

extern "C" void kernel_launch(void* const* d_in, const int* in_sizes, int n_in,
                              void* d_out, int out_size, void* d_ws, size_t ws_size,
                              hipStream_t stream) {
    const float* Y      = (const float*)d_in[0];
    const float* semH   = (const float*)d_in[1];
    const float* orthoH = (const float*)d_in[2];
    const int*   idx    = (const int*)d_in[3];
    const void*  alpha  = d_in[4];
    const void*  beta   = d_in[5];

    float* out  = (float*)d_out;
    float* embs = out;                                   // N*D
    float* A    = out + (size_t)NROWS * DDIM;            // N*N
    float* Yout = A + (size_t)NROWS * NROWS;             // N*D

    float2* ws = (float2*)d_ws;                          // needs 2 MB

    school_compute_kernel<<<NROWS / 8, 256, 0, stream>>>(
        Y, semH, orthoH, idx, alpha, beta, embs, ws, Yout);

    school_expand_kernel<<<NROWS / 8, 256, 0, stream>>>(ws, A);
}

// Round 12
// 60.160 us; speedup vs baseline: 1.4241x; 1.1408x over previous
//
#include <hip/hip_runtime.h>

#define NROWS 8192
#define DDIM  64
#define KNN   32
#define MAXIT 100

// alpha/beta arrive as 1-element arrays; robust to int32 or float32 encoding.
__device__ __forceinline__ float scalar_val(const void* p) {
    int iv = *(const int*)p;
    if (iv > -1000000 && iv < 1000000) return (float)iv;
    return *(const float*)p;
}

// One block = 8 rows, half-wave (32 lanes) per row. Fused champion structure
// (R9, 63.4us): loads+compute front, embs BEFORE the store stream (in-order
// vmcnt!), unconditional merged zero+scatter stream last.
// This round: DS-op diet for the front.
//  - distances: quad-per-column batches; only xor1/xor2 reduces (DPP, no DS)
//  - Newton: pos-count via ballot+popc (no shfl tree for the count)
__global__ __launch_bounds__(256, 4) void school_fused_kernel(
    const float* __restrict__ Y,
    const float* __restrict__ semH,
    const float* __restrict__ orthoH,
    const int*   __restrict__ idx,
    const void*  alpha_p,
    const void*  beta_p,
    float* __restrict__ embs,   // N*D
    float* __restrict__ A,      // N*N
    float* __restrict__ Yout)   // N*D
{
    __shared__ int    col_s[8][KNN];
    __shared__ float  ad_s[8][KNN];
    __shared__ float2 cw_s[8][KNN];   // packed {bitcast(col), w_deduped}

    const int tid  = threadIdx.x;
    const int j    = tid & 31;      // lane within half-wave = neighbor slot
    const int r    = tid >> 5;      // row-within-block, 0..7 (half-wave id)
    const int row0 = blockIdx.x * 8;
    const int row  = row0 + r;

    const float alpha = scalar_val(alpha_p);
    const float beta  = scalar_val(beta_p);

    // ---- Phase 0: neighbor ids -> LDS ----
    const int col = idx[row * 64 + 1 + j];       // idxa0 = idx[:, 1:33]
    col_s[r][j] = col;

    // ---- Phase 1: distances, quad-per-column ----
    // Quad Q (lanes 4Q..4Q+3 of the half-wave) handles column b*8+Q in batch
    // b. Lane p of the quad covers row elements {p+4ph : ph=0..3} (float4s).
    // Reduce within quad via xor1/xor2 only (DPP quad-perm -> VALU, no DS).
    const float4* Y4 = (const float4*)Y;
    const float4* O4 = (const float4*)orthoH;
    const int p = j & 3;            // quad lane
    const int Q = j >> 2;           // quad id 0..7

    float4 oy0 = Y4[(size_t)row * 16 + p +  0];
    float4 oy1 = Y4[(size_t)row * 16 + p +  4];
    float4 oy2 = Y4[(size_t)row * 16 + p +  8];
    float4 oy3 = Y4[(size_t)row * 16 + p + 12];
    float4 oo0 = O4[(size_t)row * 16 + p +  0];
    float4 oo1 = O4[(size_t)row * 16 + p +  4];
    float4 oo2 = O4[(size_t)row * 16 + p +  8];
    float4 oo3 = O4[(size_t)row * 16 + p + 12];

    #pragma unroll 2
    for (int b = 0; b < 4; ++b) {
        const int cidx = b * 8 + Q;
        const int c = col_s[r][cidx];
        float dY = 0.f, dO = 0.f;
        #define ACC_PH(ph, oy, oo)                                          \
        {                                                                   \
            float4 gY = Y4[(size_t)c * 16 + p + 4 * ph];                    \
            float4 gO = O4[(size_t)c * 16 + p + 4 * ph];                    \
            float ex = oy.x - gY.x, ey = oy.y - gY.y,                       \
                  ez = oy.z - gY.z, ew = oy.w - gY.w;                       \
            dY += ex * ex + ey * ey + ez * ez + ew * ew;                    \
            ex = oo.x - gO.x; ey = oo.y - gO.y;                             \
            ez = oo.z - gO.z; ew = oo.w - gO.w;                             \
            dO += ex * ex + ey * ey + ez * ez + ew * ew;                    \
        }
        ACC_PH(0, oy0, oo0)
        ACC_PH(1, oy1, oo1)
        ACC_PH(2, oy2, oo2)
        ACC_PH(3, oy3, oo3)
        #undef ACC_PH
        // quad reduce: xor1 + xor2 (DPP)
        dY += __shfl_xor(dY, 1, 64);
        dY += __shfl_xor(dY, 2, 64);
        dO += __shfl_xor(dO, 1, 64);
        dO += __shfl_xor(dO, 2, 64);
        if (p == 0) {
            float dfv = sqrtf(dY + 1e-8f);          // dfi (from Y)
            float dxv = sqrtf(dO + 1e-8f);          // dxi (from ortho_H)
            ad_s[r][cidx] = -(dxv + beta * dfv) / (2.f * alpha);
        }
    }
    const float ad = ad_s[r][j];

    // ---- Phase 2: simplex projection (32 lanes = one row) ----
    float s = ad;
    #pragma unroll
    for (int mm = 1; mm <= 16; mm <<= 1) s += __shfl_xor(s, mm, 64);
    const float v0 = ad - s * (1.f / 32.f) + (1.f / 32.f);

    // Newton with tolerance exit; pos-count via ballot (no shfl tree).
    const unsigned long long halfmask = 0xFFFFFFFFull << (tid & 32);
    float lam = 0.f;
    #pragma unroll 1
    for (int it = 0; it < MAXIT; ++it) {
        float v1 = v0 - lam;
        bool pos = v1 > 0.f;
        float pp = pos ? v1 : 0.f;
        #pragma unroll
        for (int mm = 1; mm <= 16; mm <<= 1) pp += __shfl_xor(pp, mm, 64);
        float c = (float)__popcll(__ballot(pos ? 1 : 0) & halfmask);
        float step = (pp - 1.f) / fmaxf(c, 1.f);
        lam += step;
        if (__all(fabsf(step) <= 1e-6f ? 1 : 0)) break;
    }
    const float w = fmaxf(v0 - lam, 0.f);

    // ---- Phase 3: dedupe (np fancy-assignment: last j wins) ----
    bool dead = false;
    for (int jj = j + 1; jj < 32; ++jj)
        dead |= (col_s[r][jj] == col);
    cw_s[r][j] = make_float2(__int_as_float(col), dead ? 0.f : w);

    // ---- Phase 4: embs_hom[row] = sum_j w_j * semH[col_j]  (gathers issued
    //      BEFORE the store stream -> no vmcnt coupling) ----
    {
        float2 acc = make_float2(0.f, 0.f);
        const float2* H2 = (const float2*)semH;
        #pragma unroll 4
        for (int jj = 0; jj < KNN; ++jj) {
            float2 cw = cw_s[r][jj];
            int   c   = __float_as_int(cw.x);
            float wv  = cw.y;
            float2 h = H2[(size_t)c * 32 + j];
            acc.x += wv * h.x;
            acc.y += wv * h.y;
        }
        ((float2*)embs)[(size_t)row * 32 + j] = acc;
    }

    // ---- Phase 5: Y passthrough ----
    {
        const float2* Y2 = (const float2*)(Y + (size_t)row0 * DDIM);
        float2* O2 = (float2*)(Yout + (size_t)row0 * DDIM);
        O2[tid] = Y2[tid];
    }

    // ---- Phase 6: k-slot scan (ascending jj => ascending apply = last-wins)
    // Lane j owns float4 chunks i = 32*ss + j; col c -> owner (c>>2)&31,
    // ss = c>>7, pos = c&3.
    unsigned k0 = 0xFFFFFFFFu, k1 = 0xFFFFFFFFu, k2 = 0xFFFFFFFFu, k3 = 0xFFFFFFFFu;
    float f0 = 0.f, f1 = 0.f, f2 = 0.f, f3 = 0.f;
    int nhit = 0;
    #pragma unroll 1
    for (int jj = 0; jj < 32; ++jj) {
        float2 cw = cw_s[r][jj];
        int c = __float_as_int(cw.x);
        if (((c >> 2) & 31) == j) {
            unsigned key = ((unsigned)(c >> 7) << 2) | (unsigned)(c & 3);
            float wv = cw.y;
            k3 = (nhit == 3) ? key : k3;  f3 = (nhit == 3) ? wv : f3;
            k2 = (nhit == 2) ? key : k2;  f2 = (nhit == 2) ? wv : f2;
            k1 = (nhit == 1) ? key : k1;  f1 = (nhit == 1) ? wv : f1;
            k0 = (nhit == 0) ? key : k0;  f0 = (nhit == 0) ? wv : f0;
            nhit++;
        }
    }

    // ---- Phase 7: merged zero+scatter stream (unconditional 64 float4/lane)
    {
        float4* Arow4 = (float4*)(A + (size_t)row * NROWS);
        #pragma unroll 4
        for (int ss = 0; ss < 64; ++ss) {
            float4 v = make_float4(0.f, 0.f, 0.f, 0.f);
            #define APPLY_SLOT(kk, ff)                                   \
                if ((kk >> 2) == (unsigned)ss) {                         \
                    int p_ = (int)(kk & 3u);                             \
                    v.x = (p_ == 0) ? ff : v.x;                          \
                    v.y = (p_ == 1) ? ff : v.y;                          \
                    v.z = (p_ == 2) ? ff : v.z;                          \
                    v.w = (p_ == 3) ? ff : v.w;                          \
                }
            APPLY_SLOT(k0, f0)
            APPLY_SLOT(k1, f1)
            APPLY_SLOT(k2, f2)
            APPLY_SLOT(k3, f3)
            #undef APPLY_SLOT
            Arow4[(ss << 5) + j] = v;
        }
    }

    // ---- Phase 8: rare overflow (>4 cols on one lane): ordered dword fixups
    if (nhit > 4) {
        asm volatile("s_waitcnt vmcnt(0)" ::: "memory");
        int cnt = 0;
        for (int jj = 0; jj < 32; ++jj) {
            float2 cw = cw_s[r][jj];
            int c = __float_as_int(cw.x);
            if (((c >> 2) & 31) == j) {
                if (cnt >= 4) {
                    A[(size_t)row * NROWS + c] = cw.y;
                    asm volatile("s_waitcnt vmcnt(0)" ::: "memory");
                }
                cnt++;
            }
        }
    }
}

extern "C" void kernel_launch(void* const* d_in, const int* in_sizes, int n_in,
                              void* d_out, int out_size, void* d_ws, size_t ws_size,
                              hipStream_t stream) {
    const float* Y      = (const float*)d_in[0];
    const float* semH   = (const float*)d_in[1];
    const float* orthoH = (const float*)d_in[2];
    const int*   idx    = (const int*)d_in[3];
    const void*  alpha  = d_in[4];
    const void*  beta   = d_in[5];

    float* out  = (float*)d_out;
    float* embs = out;                                   // N*D
    float* A    = out + (size_t)NROWS * DDIM;            // N*N
    float* Yout = A + (size_t)NROWS * NROWS;             // N*D

    school_fused_kernel<<<NROWS / 8, 256, 0, stream>>>(
        Y, semH, orthoH, idx, alpha, beta, embs, A, Yout);
}